// Round 2
// baseline (537.661 us; speedup 1.0000x reference)
//
#include <hip/hip_runtime.h>
#include <hip/hip_bf16.h>

#define BB 4
#define SS 2048
#define DD 1024
#define HH 16
#define DHH 64

typedef __attribute__((ext_vector_type(8))) short short8;
typedef __attribute__((ext_vector_type(4))) float floatx4;

__device__ inline short f2bf(float x) {
  union { float f; unsigned u; } v; v.f = x;
  unsigned r = v.u + 0x7FFFu + ((v.u >> 16) & 1u);
  return (short)(r >> 16);
}
__device__ inline float bf2f(short x) {
  union { unsigned u; float f; } v;
  v.u = ((unsigned)(unsigned short)x) << 16;
  return v.f;
}

// ---------------- f32 -> bf16 conversion (vectorized) ----------------
__global__ __launch_bounds__(256) void cvt_kernel(const float* __restrict__ in,
                                                  short* __restrict__ out, int n4) {
  int i = blockIdx.x * 256 + threadIdx.x;
  if (i >= n4) return;
  float4 v = ((const float4*)in)[i];
  short4 o;
  o.x = f2bf(v.x); o.y = f2bf(v.y); o.z = f2bf(v.z); o.w = f2bf(v.w);
  ((short4*)out)[i] = o;
}

// ---------------- weight transpose + convert (+scale) ----------------
__global__ __launch_bounds__(256) void wtrans_kernel(const float* __restrict__ in,
                                                     short* __restrict__ out, float scale) {
  __shared__ float tile[16][17];
  int tx = threadIdx.x & 15, ty = threadIdx.x >> 4;
  int k = blockIdx.y * 16 + ty;
  int n = blockIdx.x * 16 + tx;
  tile[ty][tx] = in[(size_t)k * 1024 + n];
  __syncthreads();
  int n2 = blockIdx.x * 16 + ty;
  int k2 = blockIdx.y * 16 + tx;
  out[(size_t)n2 * 1024 + k2] = f2bf(tile[tx][ty] * scale);
}

// ---------------- bf16 MFMA GEMM: C[M,N] = A[M,K] @ Bt[N,K]^T ----------------
template<int OUT_F32>
__global__ __launch_bounds__(256) void gemm_kernel(const short* __restrict__ A,
                                                   const short* __restrict__ Bt,
                                                   void* __restrict__ Cout,
                                                   int M, int N, int K) {
  __shared__ short As[128][48];
  __shared__ short Bs[128][48];
  const int t = threadIdx.x;
  const int lane = t & 63, wave = t >> 6;
  const int wr = wave >> 1, wc = wave & 1;
  const int l15 = lane & 15, l4 = lane >> 4;

  floatx4 acc[4][4];
#pragma unroll
  for (int i = 0; i < 4; ++i)
#pragma unroll
    for (int j = 0; j < 4; ++j) acc[i][j] = (floatx4){0.f, 0.f, 0.f, 0.f};

  const short* Ag = A + (size_t)blockIdx.x * 128 * K;
  const short* Bg = Bt + (size_t)blockIdx.y * 128 * K;
  const int stRow = t >> 2;
  const int stG = (t & 3) * 8;
  const int rbase = wr * 64 + l15;
  const int cbase = wc * 64 + l15;
  const int koff = l4 * 8;

  for (int k0 = 0; k0 < K; k0 += 32) {
    __syncthreads();
#pragma unroll
    for (int i = 0; i < 2; ++i) {
      int row = stRow + i * 64;
      *(short8*)&As[row][stG] = *(const short8*)&Ag[(size_t)row * K + k0 + stG];
      *(short8*)&Bs[row][stG] = *(const short8*)&Bg[(size_t)row * K + k0 + stG];
    }
    __syncthreads();
    short8 af[4], bfr[4];
#pragma unroll
    for (int mi = 0; mi < 4; ++mi) af[mi] = *(const short8*)&As[rbase + mi * 16][koff];
#pragma unroll
    for (int ni = 0; ni < 4; ++ni) bfr[ni] = *(const short8*)&Bs[cbase + ni * 16][koff];
#pragma unroll
    for (int mi = 0; mi < 4; ++mi)
#pragma unroll
      for (int ni = 0; ni < 4; ++ni)
        acc[mi][ni] = __builtin_amdgcn_mfma_f32_16x16x32_bf16(af[mi], bfr[ni], acc[mi][ni], 0, 0, 0);
  }

  const int row0 = blockIdx.x * 128 + wr * 64 + l4 * 4;
  const int col0 = blockIdx.y * 128 + wc * 64 + l15;
  if (OUT_F32) {
    float* Cf = (float*)Cout;
#pragma unroll
    for (int mi = 0; mi < 4; ++mi)
#pragma unroll
      for (int ni = 0; ni < 4; ++ni)
#pragma unroll
        for (int r = 0; r < 4; ++r)
          Cf[(size_t)(row0 + mi * 16 + r) * N + col0 + ni * 16] = acc[mi][ni][r];
  } else {
    short* Cs = (short*)Cout;
#pragma unroll
    for (int mi = 0; mi < 4; ++mi)
#pragma unroll
      for (int ni = 0; ni < 4; ++ni)
#pragma unroll
        for (int r = 0; r < 4; ++r)
          Cs[(size_t)(row0 + mi * 16 + r) * N + col0 + ni * 16] = f2bf(acc[mi][ni][r]);
  }
}

// ---------------- flash attention ----------------
// grid: (B*H, S/64). 256 threads = 4 waves; wave w owns q rows [q0+16w, q0+16w+16).
// LDS strides 66 shorts (33 dwords): bank = (row + word_in_row) % 32 -> near-even
// for both the b128 fragment reads and the scalar V-transpose writes.
__global__ __launch_bounds__(256) void attn_kernel(const short* __restrict__ Q,
                                                   const short* __restrict__ K,
                                                   const short* __restrict__ V,
                                                   const short* __restrict__ biasb,
                                                   short* __restrict__ O) {
  __shared__ short Klds[64][66];
  __shared__ short Vt[64][66];
  __shared__ short Blds[64][66];
  __shared__ short Plds[4][16][66];

  const int t = threadIdx.x;
  const int lane = t & 63, wave = t >> 6;
  const int b = blockIdx.x >> 4, h = blockIdx.x & 15;
  const int q0 = blockIdx.y * 64;
  const int l15 = lane & 15, l4 = lane >> 4;

  const size_t headoff = (size_t)h * DHH;
  const short* Qb = Q + (size_t)b * SS * DD + headoff;
  const short* Kb = K + (size_t)b * SS * DD + headoff;
  const short* Vb = V + (size_t)b * SS * DD + headoff;
  const short* Bb = biasb + ((size_t)b * SS + q0) * SS;

  short8 aq[2];
  {
    int qrow = q0 + wave * 16 + l15;
    aq[0] = *(const short8*)&Qb[(size_t)qrow * DD + l4 * 8];
    aq[1] = *(const short8*)&Qb[(size_t)qrow * DD + 32 + l4 * 8];
  }

  floatx4 acc_o[4];
#pragma unroll
  for (int dg = 0; dg < 4; ++dg) acc_o[dg] = (floatx4){0.f, 0.f, 0.f, 0.f};
  float mrun[4], ssum[4];
#pragma unroll
  for (int r = 0; r < 4; ++r) { mrun[r] = -1e30f; ssum[r] = 0.f; }

  for (int kv0 = 0; kv0 < SS; kv0 += 64) {
    __syncthreads();  // previous iter's LDS reads done before restaging
#pragma unroll
    for (int i = 0; i < 2; ++i) {
      int idx = t + i * 256;
      int kv = idx >> 3, g = (idx & 7) * 8;
      *(short8*)&Klds[kv][g] = *(const short8*)&Kb[(size_t)(kv0 + kv) * DD + g];
      short8 vv = *(const short8*)&Vb[(size_t)(kv0 + kv) * DD + g];
#pragma unroll
      for (int jj = 0; jj < 8; ++jj) Vt[g + jj][kv] = vv[jj];
      // bias tile: row kv -> q-local row, col g -> kv-local col
      *(short8*)&Blds[kv][g] = *(const short8*)&Bb[(size_t)kv * SS + kv0 + g];
    }
    __syncthreads();

    // QK^T: s[g] is 16q x 16kv fragment (cols kv0+16g+l15, rows q0+16w+4*l4+r)
    floatx4 s[4];
#pragma unroll
    for (int g = 0; g < 4; ++g) {
      floatx4 a = (floatx4){0.f, 0.f, 0.f, 0.f};
      a = __builtin_amdgcn_mfma_f32_16x16x32_bf16(
          aq[0], *(const short8*)&Klds[g * 16 + l15][l4 * 8], a, 0, 0, 0);
      a = __builtin_amdgcn_mfma_f32_16x16x32_bf16(
          aq[1], *(const short8*)&Klds[g * 16 + l15][32 + l4 * 8], a, 0, 0, 0);
      s[g] = a;
    }

    // bias add (from LDS) + running max
    float tmax[4];
#pragma unroll
    for (int r = 0; r < 4; ++r) tmax[r] = -1e30f;
#pragma unroll
    for (int g = 0; g < 4; ++g)
#pragma unroll
      for (int r = 0; r < 4; ++r) {
        float val = s[g][r] + bf2f(Blds[wave * 16 + l4 * 4 + r][g * 16 + l15]);
        s[g][r] = val;
        tmax[r] = fmaxf(tmax[r], val);
      }
#pragma unroll
    for (int r = 0; r < 4; ++r)
      for (int m = 1; m < 16; m <<= 1) tmax[r] = fmaxf(tmax[r], __shfl_xor(tmax[r], m));

    float fac[4], rsum[4];
#pragma unroll
    for (int r = 0; r < 4; ++r) {
      float mnew = fmaxf(mrun[r], tmax[r]);
      fac[r] = __expf(mrun[r] - mnew);
      mrun[r] = mnew;
      rsum[r] = 0.f;
    }
#pragma unroll
    for (int g = 0; g < 4; ++g)
#pragma unroll
      for (int r = 0; r < 4; ++r) {
        float p = __expf(s[g][r] - mrun[r]);
        s[g][r] = p;
        rsum[r] += p;
      }
#pragma unroll
    for (int r = 0; r < 4; ++r) {
      for (int m = 1; m < 16; m <<= 1) rsum[r] += __shfl_xor(rsum[r], m);
      ssum[r] = ssum[r] * fac[r] + rsum[r];
    }
#pragma unroll
    for (int dg = 0; dg < 4; ++dg)
#pragma unroll
      for (int r = 0; r < 4; ++r) acc_o[dg][r] *= fac[r];

    // P -> per-wave LDS (bf16); no barrier needed (wave-private buffer,
    // compiler inserts the lgkmcnt wait for the aliasing ds_read below).
#pragma unroll
    for (int g = 0; g < 4; ++g)
#pragma unroll
      for (int r = 0; r < 4; ++r)
        Plds[wave][l4 * 4 + r][g * 16 + l15] = f2bf(s[g][r]);

#pragma unroll
    for (int kk = 0; kk < 2; ++kk) {
      short8 pf = *(const short8*)&Plds[wave][l15][kk * 32 + l4 * 8];
#pragma unroll
      for (int dg = 0; dg < 4; ++dg) {
        short8 vf = *(const short8*)&Vt[dg * 16 + l15][kk * 32 + l4 * 8];
        acc_o[dg] = __builtin_amdgcn_mfma_f32_16x16x32_bf16(pf, vf, acc_o[dg], 0, 0, 0);
      }
    }
  }

  short* Ob = O + (size_t)b * SS * DD + headoff;
#pragma unroll
  for (int r = 0; r < 4; ++r) {
    float inv = 1.0f / ssum[r];
    int orow = q0 + wave * 16 + l4 * 4 + r;
#pragma unroll
    for (int dg = 0; dg < 4; ++dg)
      Ob[(size_t)orow * DD + dg * 16 + l15] = f2bf(acc_o[dg][r] * inv);
  }
}

// ---------------- launch ----------------
extern "C" void kernel_launch(void* const* d_in, const int* in_sizes, int n_in,
                              void* d_out, int out_size, void* d_ws, size_t ws_size,
                              hipStream_t stream) {
  const float* qa   = (const float*)d_in[0];
  const float* ma   = (const float*)d_in[1];
  const float* bias = (const float*)d_in[2];
  const float* Wq   = (const float*)d_in[3];
  const float* Wk   = (const float*)d_in[4];
  const float* Wv   = (const float*)d_in[5];
  const float* Wo   = (const float*)d_in[6];
  float* out = (float*)d_out;

  char* ws = (char*)d_ws;
  size_t off = 0;
  auto alloc = [&](size_t bytes) {
    char* p = ws + off;
    off += (bytes + 255) & ~(size_t)255;
    return p;
  };
  const size_t nQKV = (size_t)BB * SS * DD;
  short* qa_bf   = (short*)alloc(nQKV * 2);
  short* ma_bf   = (short*)alloc(nQKV * 2);
  short* bias_bf = (short*)alloc((size_t)BB * SS * SS * 2);
  short* Wqt = (short*)alloc((size_t)DD * DD * 2);
  short* Wkt = (short*)alloc((size_t)DD * DD * 2);
  short* Wvt = (short*)alloc((size_t)DD * DD * 2);
  short* Wot = (short*)alloc((size_t)DD * DD * 2);
  short* Qp  = (short*)alloc(nQKV * 2);
  short* Kp  = (short*)alloc(nQKV * 2);
  short* Vp  = (short*)alloc(nQKV * 2);
  short* AOp = (short*)alloc(nQKV * 2);

  int n4a = (int)(nQKV / 4);
  int n4b = BB * SS * SS / 4;
  cvt_kernel<<<(n4a + 255) / 256, 256, 0, stream>>>(qa, qa_bf, n4a);
  cvt_kernel<<<(n4a + 255) / 256, 256, 0, stream>>>(ma, ma_bf, n4a);
  cvt_kernel<<<(n4b + 255) / 256, 256, 0, stream>>>(bias, bias_bf, n4b);

  dim3 tg(64, 64);
  wtrans_kernel<<<tg, 256, 0, stream>>>(Wq, Wqt, 0.125f);
  wtrans_kernel<<<tg, 256, 0, stream>>>(Wk, Wkt, 1.0f);
  wtrans_kernel<<<tg, 256, 0, stream>>>(Wv, Wvt, 1.0f);
  wtrans_kernel<<<tg, 256, 0, stream>>>(Wo, Wot, 1.0f);

  dim3 gg(BB * SS / 128, DD / 128);
  gemm_kernel<0><<<gg, 256, 0, stream>>>(qa_bf, Wqt, Qp, BB * SS, DD, DD);
  gemm_kernel<0><<<gg, 256, 0, stream>>>(ma_bf, Wkt, Kp, BB * SS, DD, DD);
  gemm_kernel<0><<<gg, 256, 0, stream>>>(ma_bf, Wvt, Vp, BB * SS, DD, DD);

  attn_kernel<<<dim3(BB * HH, SS / 64), 256, 0, stream>>>(Qp, Kp, Vp, bias_bf, AOp);

  gemm_kernel<1><<<gg, 256, 0, stream>>>(AOp, Wot, out, BB * SS, DD, DD);
}

// Round 3
// 438.114 us; speedup vs baseline: 1.2272x; 1.2272x over previous
//
#include <hip/hip_runtime.h>
#include <hip/hip_bf16.h>

#define BB 4
#define SS 2048
#define DD 1024
#define HH 16
#define DHH 64

typedef __attribute__((ext_vector_type(8))) short short8;
typedef __attribute__((ext_vector_type(4))) float floatx4;

__device__ inline short f2bf(float x) {
  union { float f; unsigned u; } v; v.f = x;
  unsigned r = v.u + 0x7FFFu + ((v.u >> 16) & 1u);
  return (short)(r >> 16);
}
__device__ inline float bf2f(short x) {
  union { unsigned u; float f; } v;
  v.u = ((unsigned)(unsigned short)x) << 16;
  return v.f;
}

typedef __attribute__((address_space(1))) const unsigned int GUI;
typedef __attribute__((address_space(3))) unsigned int LUI;
__device__ inline void gload16(const void* g, void* l) {
  __builtin_amdgcn_global_load_lds((GUI*)g, (LUI*)l, 16, 0, 0);
}

// ---------------- f32 -> bf16 conversion (vectorized, optional scale) ---------
__global__ __launch_bounds__(256) void cvt_kernel(const float* __restrict__ in,
                                                  short* __restrict__ out, int n4,
                                                  float scale) {
  int i = blockIdx.x * 256 + threadIdx.x;
  if (i >= n4) return;
  float4 v = ((const float4*)in)[i];
  short4 o;
  o.x = f2bf(v.x * scale); o.y = f2bf(v.y * scale);
  o.z = f2bf(v.z * scale); o.w = f2bf(v.w * scale);
  ((short4*)out)[i] = o;
}

// ---------------- weight transpose + convert (+scale) ----------------
__global__ __launch_bounds__(256) void wtrans_kernel(const float* __restrict__ in,
                                                     short* __restrict__ out, float scale) {
  __shared__ float tile[16][17];
  int tx = threadIdx.x & 15, ty = threadIdx.x >> 4;
  int k = blockIdx.y * 16 + ty;
  int n = blockIdx.x * 16 + tx;
  tile[ty][tx] = in[(size_t)k * 1024 + n];
  __syncthreads();
  int n2 = blockIdx.x * 16 + ty;
  int k2 = blockIdx.y * 16 + tx;
  out[(size_t)n2 * 1024 + k2] = f2bf(tile[tx][ty] * scale);
}

// ---------------- V transpose: [B][S][1024] -> [B][1024][S] (bf16, int-packed) ---
__global__ __launch_bounds__(256) void vtrans_kernel(const short* __restrict__ in,
                                                     short* __restrict__ out) {
  __shared__ int tile[64][33];
  const int t = threadIdx.x;
  const int b = blockIdx.z;
  const int s0 = blockIdx.x * 64, d0 = blockIdx.y * 64;
  const int* gin = (const int*)(in + (size_t)b * SS * DD);   // [S][512] ints
  int* gout = (int*)(out + (size_t)b * DD * SS);             // [1024][1024] ints
#pragma unroll
  for (int i = 0; i < 8; ++i) {
    int idx = t + i * 256;
    int row = idx >> 5, col = idx & 31;   // s-local, d-pair col
    tile[row][col] = gin[(size_t)(s0 + row) * 512 + (d0 >> 1) + col];
  }
  __syncthreads();
#pragma unroll
  for (int i = 0; i < 8; ++i) {
    int idx = t + i * 256;
    int d = idx >> 5, spc = idx & 31;     // d-local, s-pair col
    int a = tile[2 * spc][d >> 1];
    int c = tile[2 * spc + 1][d >> 1];
    int o = (d & 1) ? (((a >> 16) & 0xffff) | (c & 0xffff0000))
                    : ((a & 0xffff) | (c << 16));
    gout[(size_t)(d0 + d) * (SS / 2) + (s0 >> 1) + spc] = o;
  }
}

// ---------------- bf16 MFMA GEMM: C[M,N] = A[M,K] @ Bt[N,K]^T ----------------
// 128x128 tile, BK=32, 4 waves, global_load_lds(16B) staging, linear LDS.
template<int OUT_F32>
__global__ __launch_bounds__(256) void gemm_kernel(const short* __restrict__ A,
                                                   const short* __restrict__ Bt,
                                                   void* __restrict__ Cout,
                                                   int M, int N, int K) {
  __shared__ alignas(16) short As[128][32];
  __shared__ alignas(16) short Bs[128][32];
  const int t = threadIdx.x;
  const int lane = t & 63, wave = t >> 6;
  const int wr = wave >> 1, wc = wave & 1;
  const int l15 = lane & 15, l4 = lane >> 4;

  floatx4 acc[4][4];
#pragma unroll
  for (int i = 0; i < 4; ++i)
#pragma unroll
    for (int j = 0; j < 4; ++j) acc[i][j] = (floatx4){0.f, 0.f, 0.f, 0.f};

  const short* Ag = A + (size_t)blockIdx.x * 128 * K;
  const short* Bg = Bt + (size_t)blockIdx.y * 128 * K;
  const int o0 = t * 16, o1 = t * 16 + 4096;      // LDS byte offsets
  const int r0 = o0 >> 6, c0 = (o0 >> 1) & 31;    // row, col(short)
  const int r1 = o1 >> 6, c1 = (o1 >> 1) & 31;
  const int rbase = wr * 64 + l15;
  const int cbase = wc * 64 + l15;
  const int koff = l4 * 8;

  for (int k0 = 0; k0 < K; k0 += 32) {
    __syncthreads();
    gload16(&Ag[(size_t)r0 * K + k0 + c0], (char*)As + o0);
    gload16(&Bg[(size_t)r0 * K + k0 + c0], (char*)Bs + o0);
    gload16(&Ag[(size_t)r1 * K + k0 + c1], (char*)As + o1);
    gload16(&Bg[(size_t)r1 * K + k0 + c1], (char*)Bs + o1);
    __syncthreads();
    short8 af[4], bfr[4];
#pragma unroll
    for (int mi = 0; mi < 4; ++mi) af[mi] = *(const short8*)&As[rbase + mi * 16][koff];
#pragma unroll
    for (int ni = 0; ni < 4; ++ni) bfr[ni] = *(const short8*)&Bs[cbase + ni * 16][koff];
#pragma unroll
    for (int mi = 0; mi < 4; ++mi)
#pragma unroll
      for (int ni = 0; ni < 4; ++ni)
        acc[mi][ni] = __builtin_amdgcn_mfma_f32_16x16x32_bf16(af[mi], bfr[ni], acc[mi][ni], 0, 0, 0);
  }

  const int row0 = blockIdx.x * 128 + wr * 64 + l4 * 4;
  const int col0 = blockIdx.y * 128 + wc * 64 + l15;
  if (OUT_F32) {
    float* Cf = (float*)Cout;
#pragma unroll
    for (int mi = 0; mi < 4; ++mi)
#pragma unroll
      for (int ni = 0; ni < 4; ++ni)
#pragma unroll
        for (int r = 0; r < 4; ++r)
          Cf[(size_t)(row0 + mi * 16 + r) * N + col0 + ni * 16] = acc[mi][ni][r];
  } else {
    short* Cs = (short*)Cout;
#pragma unroll
    for (int mi = 0; mi < 4; ++mi)
#pragma unroll
      for (int ni = 0; ni < 4; ++ni)
#pragma unroll
        for (int r = 0; r < 4; ++r)
          Cs[(size_t)(row0 + mi * 16 + r) * N + col0 + ni * 16] = f2bf(acc[mi][ni][r]);
  }
}

// ---------------- flash attention ----------------
// grid: (B*H, S/64). 4 waves; wave w owns q rows [q0+16w, q0+16w+16).
// K/V^T/P in [64][64] LDS, XOR-swizzled per 16B chunk (chunk ^= row&7).
// Bias tile [64][72] (aligned stride, scalar reads) feeds MFMA C-init.
// Softmax in log2 domain (log2e folded into Wq scale and bias cvt).
__global__ __launch_bounds__(256) void attn_kernel(const short* __restrict__ Q,
                                                   const short* __restrict__ K,
                                                   const short* __restrict__ VT,
                                                   const short* __restrict__ biasb,
                                                   short* __restrict__ O) {
  __shared__ alignas(16) short Klds[64][64];
  __shared__ alignas(16) short Vtl[64][64];
  __shared__ alignas(16) short Blds[64][72];
  __shared__ alignas(16) short Plds[4][16][64];

  const int t = threadIdx.x;
  const int lane = t & 63, wave = t >> 6;
  const int b = blockIdx.x >> 4, h = blockIdx.x & 15;
  const int q0 = blockIdx.y * 64;
  const int l15 = lane & 15, l4 = lane >> 4;

  const short* Qb = Q + (size_t)b * SS * DD + h * DHH;
  const short* Kb = K + (size_t)b * SS * DD + h * DHH;
  const short* VTb = VT + ((size_t)b * DD + h * DHH) * SS;    // [64 d][S]
  const short* Bb = biasb + ((size_t)b * SS + q0) * SS;

  short8 aq[2];
  {
    int qrow = q0 + wave * 16 + l15;
    aq[0] = *(const short8*)&Qb[(size_t)qrow * DD + l4 * 8];
    aq[1] = *(const short8*)&Qb[(size_t)qrow * DD + 32 + l4 * 8];
  }

  floatx4 acc_o[4];
#pragma unroll
  for (int dg = 0; dg < 4; ++dg) acc_o[dg] = (floatx4){0.f, 0.f, 0.f, 0.f};
  float mrun[4], ssum[4];
#pragma unroll
  for (int r = 0; r < 4; ++r) { mrun[r] = -1e30f; ssum[r] = 0.f; }

  // staging decomposition: idx = t + 256*i -> row = idx>>3 (8 rows/wave), c = idx&7
  const int srow0 = t >> 3, sc0 = t & 7;
  const int srow1 = (t + 256) >> 3, sc1 = sc0;

  // prologue: prefetch tile 0 into registers
  short8 kreg[2], vreg[2], breg[2];
  {
    kreg[0] = *(const short8*)&Kb[(size_t)srow0 * DD + sc0 * 8];
    kreg[1] = *(const short8*)&Kb[(size_t)srow1 * DD + sc1 * 8];
    vreg[0] = *(const short8*)&VTb[(size_t)srow0 * SS + sc0 * 8];
    vreg[1] = *(const short8*)&VTb[(size_t)srow1 * SS + sc1 * 8];
    breg[0] = *(const short8*)&Bb[(size_t)srow0 * SS + sc0 * 8];
    breg[1] = *(const short8*)&Bb[(size_t)srow1 * SS + sc1 * 8];
  }

  for (int kv0 = 0; kv0 < SS; kv0 += 64) {
    __syncthreads();  // previous iter's LDS reads complete
    // stage registers -> LDS (swizzled K/V, linear bias)
    *(short8*)&Klds[srow0][(sc0 ^ (srow0 & 7)) * 8] = kreg[0];
    *(short8*)&Klds[srow1][(sc1 ^ (srow1 & 7)) * 8] = kreg[1];
    *(short8*)&Vtl[srow0][(sc0 ^ (srow0 & 7)) * 8] = vreg[0];
    *(short8*)&Vtl[srow1][(sc1 ^ (srow1 & 7)) * 8] = vreg[1];
    *(short8*)&Blds[srow0][sc0 * 8] = breg[0];
    *(short8*)&Blds[srow1][sc1 * 8] = breg[1];
    __syncthreads();

    // prefetch next tile into regs (overlaps with compute below)
    if (kv0 + 64 < SS) {
      int kv1 = kv0 + 64;
      kreg[0] = *(const short8*)&Kb[(size_t)(kv1 + srow0) * DD + sc0 * 8];
      kreg[1] = *(const short8*)&Kb[(size_t)(kv1 + srow1) * DD + sc1 * 8];
      vreg[0] = *(const short8*)&VTb[(size_t)srow0 * SS + kv1 + sc0 * 8];
      vreg[1] = *(const short8*)&VTb[(size_t)srow1 * SS + kv1 + sc1 * 8];
      breg[0] = *(const short8*)&Bb[(size_t)srow0 * SS + kv1 + sc0 * 8];
      breg[1] = *(const short8*)&Bb[(size_t)srow1 * SS + kv1 + sc1 * 8];
    }

    // QK^T with bias as MFMA C-init
    floatx4 s[4];
#pragma unroll
    for (int g = 0; g < 4; ++g) {
      int kr = g * 16 + l15;
      floatx4 c0;
#pragma unroll
      for (int j = 0; j < 4; ++j)
        c0[j] = bf2f(Blds[wave * 16 + l4 * 4 + j][g * 16 + l15]);
      c0 = __builtin_amdgcn_mfma_f32_16x16x32_bf16(
          aq[0], *(const short8*)&Klds[kr][(l4 ^ (kr & 7)) * 8], c0, 0, 0, 0);
      c0 = __builtin_amdgcn_mfma_f32_16x16x32_bf16(
          aq[1], *(const short8*)&Klds[kr][((4 + l4) ^ (kr & 7)) * 8], c0, 0, 0, 0);
      s[g] = c0;
    }

    // online softmax (log2 domain)
    float tmax[4];
#pragma unroll
    for (int r = 0; r < 4; ++r) tmax[r] = -1e30f;
#pragma unroll
    for (int g = 0; g < 4; ++g)
#pragma unroll
      for (int r = 0; r < 4; ++r) tmax[r] = fmaxf(tmax[r], s[g][r]);
#pragma unroll
    for (int r = 0; r < 4; ++r)
      for (int m = 1; m < 16; m <<= 1) tmax[r] = fmaxf(tmax[r], __shfl_xor(tmax[r], m));

    float fac[4], rsum[4];
#pragma unroll
    for (int r = 0; r < 4; ++r) {
      float mnew = fmaxf(mrun[r], tmax[r]);
      fac[r] = exp2f(mrun[r] - mnew);
      mrun[r] = mnew;
      rsum[r] = 0.f;
    }
#pragma unroll
    for (int g = 0; g < 4; ++g)
#pragma unroll
      for (int r = 0; r < 4; ++r) {
        float p = exp2f(s[g][r] - mrun[r]);
        s[g][r] = p;
        rsum[r] += p;
      }
#pragma unroll
    for (int r = 0; r < 4; ++r) {
      for (int m = 1; m < 16; m <<= 1) rsum[r] += __shfl_xor(rsum[r], m);
      ssum[r] = ssum[r] * fac[r] + rsum[r];
    }
#pragma unroll
    for (int dg = 0; dg < 4; ++dg)
#pragma unroll
      for (int r = 0; r < 4; ++r) acc_o[dg][r] *= fac[r];

    // P -> per-wave LDS (bf16, swizzled); wave-private, no barrier needed
#pragma unroll
    for (int g = 0; g < 4; ++g)
#pragma unroll
      for (int r = 0; r < 4; ++r) {
        int prow = l4 * 4 + r, pcol = g * 16 + l15;
        Plds[wave][prow][((pcol >> 3) ^ (prow & 7)) * 8 + (pcol & 7)] = f2bf(s[g][r]);
      }

#pragma unroll
    for (int kk = 0; kk < 2; ++kk) {
      short8 pf = *(const short8*)&Plds[wave][l15][((kk * 4 + l4) ^ (l15 & 7)) * 8];
#pragma unroll
      for (int dg = 0; dg < 4; ++dg) {
        int vr = dg * 16 + l15;
        short8 vf = *(const short8*)&Vtl[vr][((kk * 4 + l4) ^ (vr & 7)) * 8];
        acc_o[dg] = __builtin_amdgcn_mfma_f32_16x16x32_bf16(pf, vf, acc_o[dg], 0, 0, 0);
      }
    }
  }

  short* Ob = O + (size_t)b * SS * DD + h * DHH;
#pragma unroll
  for (int r = 0; r < 4; ++r) {
    float inv = 1.0f / ssum[r];
    int orow = q0 + wave * 16 + l4 * 4 + r;
#pragma unroll
    for (int dg = 0; dg < 4; ++dg)
      Ob[(size_t)orow * DD + dg * 16 + l15] = f2bf(acc_o[dg][r] * inv);
  }
}

// ---------------- launch ----------------
extern "C" void kernel_launch(void* const* d_in, const int* in_sizes, int n_in,
                              void* d_out, int out_size, void* d_ws, size_t ws_size,
                              hipStream_t stream) {
  const float* qa   = (const float*)d_in[0];
  const float* ma   = (const float*)d_in[1];
  const float* bias = (const float*)d_in[2];
  const float* Wq   = (const float*)d_in[3];
  const float* Wk   = (const float*)d_in[4];
  const float* Wv   = (const float*)d_in[5];
  const float* Wo   = (const float*)d_in[6];
  float* out = (float*)d_out;

  char* ws = (char*)d_ws;
  size_t off = 0;
  auto alloc = [&](size_t bytes) {
    char* p = ws + off;
    off += (bytes + 255) & ~(size_t)255;
    return p;
  };
  const size_t nQKV = (size_t)BB * SS * DD;
  short* qa_bf   = (short*)alloc(nQKV * 2);
  short* ma_bf   = (short*)alloc(nQKV * 2);
  short* bias_bf = (short*)alloc((size_t)BB * SS * SS * 2);
  short* Wqt = (short*)alloc((size_t)DD * DD * 2);
  short* Wkt = (short*)alloc((size_t)DD * DD * 2);
  short* Wvt = (short*)alloc((size_t)DD * DD * 2);
  short* Wot = (short*)alloc((size_t)DD * DD * 2);
  short* Qp  = (short*)alloc(nQKV * 2);
  short* Kp  = (short*)alloc(nQKV * 2);
  short* Vp  = (short*)alloc(nQKV * 2);
  short* AOp = (short*)alloc(nQKV * 2);
  short* VTp = qa_bf;  // reuse: qa_bf dead after Q-projection GEMM

  const float LOG2E = 1.4426950408889634f;
  int n4a = (int)(nQKV / 4);
  int n4b = BB * SS * SS / 4;
  cvt_kernel<<<(n4a + 255) / 256, 256, 0, stream>>>(qa, qa_bf, n4a, 1.0f);
  cvt_kernel<<<(n4a + 255) / 256, 256, 0, stream>>>(ma, ma_bf, n4a, 1.0f);
  cvt_kernel<<<(n4b + 255) / 256, 256, 0, stream>>>(bias, bias_bf, n4b, LOG2E);

  dim3 tg(64, 64);
  wtrans_kernel<<<tg, 256, 0, stream>>>(Wq, Wqt, 0.125f * LOG2E);
  wtrans_kernel<<<tg, 256, 0, stream>>>(Wk, Wkt, 1.0f);
  wtrans_kernel<<<tg, 256, 0, stream>>>(Wv, Wvt, 1.0f);
  wtrans_kernel<<<tg, 256, 0, stream>>>(Wo, Wot, 1.0f);

  dim3 gg(BB * SS / 128, DD / 128);
  gemm_kernel<0><<<gg, 256, 0, stream>>>(qa_bf, Wqt, Qp, BB * SS, DD, DD);
  gemm_kernel<0><<<gg, 256, 0, stream>>>(ma_bf, Wkt, Kp, BB * SS, DD, DD);
  gemm_kernel<0><<<gg, 256, 0, stream>>>(ma_bf, Wvt, Vp, BB * SS, DD, DD);

  vtrans_kernel<<<dim3(SS / 64, DD / 64, BB), 256, 0, stream>>>(Vp, VTp);

  attn_kernel<<<dim3(BB * HH, SS / 64), 256, 0, stream>>>(Qp, Kp, VTp, bias_bf, AOp);

  gemm_kernel<1><<<gg, 256, 0, stream>>>(AOp, Wot, out, BB * SS, DD, DD);
}

// Round 4
// 352.657 us; speedup vs baseline: 1.5246x; 1.2423x over previous
//
#include <hip/hip_runtime.h>
#include <hip/hip_bf16.h>

#define BB 4
#define SS 2048
#define DD 1024
#define HH 16
#define DHH 64

typedef __attribute__((ext_vector_type(8))) short short8;
typedef __attribute__((ext_vector_type(4))) float floatx4;
typedef __attribute__((ext_vector_type(16))) float floatx16;
typedef __attribute__((ext_vector_type(4))) int int4v;

__device__ inline short f2bf(float x) {
  union { float f; unsigned u; } v; v.f = x;
  unsigned r = v.u + 0x7FFFu + ((v.u >> 16) & 1u);
  return (short)(r >> 16);
}
__device__ inline float bf2f(short x) {
  union { unsigned u; float f; } v;
  v.u = ((unsigned)(unsigned short)x) << 16;
  return v.f;
}
__device__ inline int cvtpk(float lo, float hi) {
  int r;
  asm("v_cvt_pk_bf16_f32 %0, %1, %2" : "=v"(r) : "v"(lo), "v"(hi));
  return r;
}

typedef __attribute__((address_space(1))) const unsigned int GUI;
typedef __attribute__((address_space(3))) unsigned int LUI;
__device__ inline void gload16(const void* g, void* l) {
  __builtin_amdgcn_global_load_lds((GUI*)g, (LUI*)l, 16, 0, 0);
}

// ---------------- f32 -> bf16 conversion ----------------
__global__ __launch_bounds__(256) void cvt_kernel(const float* __restrict__ in,
                                                  short* __restrict__ out, int n4,
                                                  float scale) {
  int i = blockIdx.x * 256 + threadIdx.x;
  if (i >= n4) return;
  float4 v = ((const float4*)in)[i];
  short4 o;
  o.x = f2bf(v.x * scale); o.y = f2bf(v.y * scale);
  o.z = f2bf(v.z * scale); o.w = f2bf(v.w * scale);
  ((short4*)out)[i] = o;
}

// ---------------- weight transpose + convert (+scale) ----------------
__global__ __launch_bounds__(256) void wtrans_kernel(const float* __restrict__ in,
                                                     short* __restrict__ out, float scale) {
  __shared__ float tile[16][17];
  int tx = threadIdx.x & 15, ty = threadIdx.x >> 4;
  int k = blockIdx.y * 16 + ty;
  int n = blockIdx.x * 16 + tx;
  tile[ty][tx] = in[(size_t)k * 1024 + n];
  __syncthreads();
  int n2 = blockIdx.x * 16 + ty;
  int k2 = blockIdx.y * 16 + tx;
  out[(size_t)n2 * 1024 + k2] = f2bf(tile[tx][ty] * scale);
}

// ---------------- bias transpose+cvt: [B][q][kv] f32 -> [B][kv][q] bf16*LOG2E ----
__global__ __launch_bounds__(256) void btrans_kernel(const float* __restrict__ in,
                                                     short* __restrict__ out, float scale) {
  __shared__ short tile[64][65];
  const int t = threadIdx.x;
  const int b = blockIdx.z;
  const int q0 = blockIdx.x * 64, kv0 = blockIdx.y * 64;
  const float* gin = in + ((size_t)b * SS + q0) * SS + kv0;
  short* gout = out + ((size_t)b * SS + kv0) * SS + q0;
#pragma unroll
  for (int i = 0; i < 16; ++i) {
    int idx = t + 256 * i;
    int row = idx >> 6, col = idx & 63;           // q-local, kv-local
    tile[col][row] = f2bf(gin[(size_t)row * SS + col] * scale);
  }
  __syncthreads();
#pragma unroll
  for (int i = 0; i < 16; ++i) {
    int idx = t + 256 * i;
    int row = idx >> 6, col = idx & 63;           // kv-local, q-local
    gout[(size_t)row * SS + col] = tile[row][col];
  }
}

// ---------------- V transpose: [B][S][1024] -> [B][1024][S] ----------------
__global__ __launch_bounds__(256) void vtrans_kernel(const short* __restrict__ in,
                                                     short* __restrict__ out) {
  __shared__ int tile[64][33];
  const int t = threadIdx.x;
  const int b = blockIdx.z;
  const int s0 = blockIdx.x * 64, d0 = blockIdx.y * 64;
  const int* gin = (const int*)(in + (size_t)b * SS * DD);
  int* gout = (int*)(out + (size_t)b * DD * SS);
#pragma unroll
  for (int i = 0; i < 8; ++i) {
    int idx = t + i * 256;
    int row = idx >> 5, col = idx & 31;
    tile[row][col] = gin[(size_t)(s0 + row) * 512 + (d0 >> 1) + col];
  }
  __syncthreads();
#pragma unroll
  for (int i = 0; i < 8; ++i) {
    int idx = t + i * 256;
    int d = idx >> 5, spc = idx & 31;
    int a = tile[2 * spc][d >> 1];
    int c = tile[2 * spc + 1][d >> 1];
    int o = (d & 1) ? (((a >> 16) & 0xffff) | (c & 0xffff0000))
                    : ((a & 0xffff) | (c << 16));
    gout[(size_t)(d0 + d) * (SS / 2) + (s0 >> 1) + spc] = o;
  }
}

// ---------------- bf16 MFMA GEMM (unchanged from r3) ----------------
template<int OUT_F32>
__global__ __launch_bounds__(256) void gemm_kernel(const short* __restrict__ A,
                                                   const short* __restrict__ Bt,
                                                   void* __restrict__ Cout,
                                                   int M, int N, int K) {
  __shared__ alignas(16) short As[128][32];
  __shared__ alignas(16) short Bs[128][32];
  const int t = threadIdx.x;
  const int lane = t & 63, wave = t >> 6;
  const int wr = wave >> 1, wc = wave & 1;
  const int l15 = lane & 15, l4 = lane >> 4;

  floatx4 acc[4][4];
#pragma unroll
  for (int i = 0; i < 4; ++i)
#pragma unroll
    for (int j = 0; j < 4; ++j) acc[i][j] = (floatx4){0.f, 0.f, 0.f, 0.f};

  const short* Ag = A + (size_t)blockIdx.x * 128 * K;
  const short* Bg = Bt + (size_t)blockIdx.y * 128 * K;
  const int o0 = t * 16, o1 = t * 16 + 4096;
  const int r0 = o0 >> 6, c0 = (o0 >> 1) & 31;
  const int r1 = o1 >> 6, c1 = (o1 >> 1) & 31;
  const int rbase = wr * 64 + l15;
  const int cbase = wc * 64 + l15;
  const int koff = l4 * 8;

  for (int k0 = 0; k0 < K; k0 += 32) {
    __syncthreads();
    gload16(&Ag[(size_t)r0 * K + k0 + c0], (char*)As + o0);
    gload16(&Bg[(size_t)r0 * K + k0 + c0], (char*)Bs + o0);
    gload16(&Ag[(size_t)r1 * K + k0 + c1], (char*)As + o1);
    gload16(&Bg[(size_t)r1 * K + k0 + c1], (char*)Bs + o1);
    __syncthreads();
    short8 af[4], bfr[4];
#pragma unroll
    for (int mi = 0; mi < 4; ++mi) af[mi] = *(const short8*)&As[rbase + mi * 16][koff];
#pragma unroll
    for (int ni = 0; ni < 4; ++ni) bfr[ni] = *(const short8*)&Bs[cbase + ni * 16][koff];
#pragma unroll
    for (int mi = 0; mi < 4; ++mi)
#pragma unroll
      for (int ni = 0; ni < 4; ++ni)
        acc[mi][ni] = __builtin_amdgcn_mfma_f32_16x16x32_bf16(af[mi], bfr[ni], acc[mi][ni], 0, 0, 0);
  }

  const int row0 = blockIdx.x * 128 + wr * 64 + l4 * 4;
  const int col0 = blockIdx.y * 128 + wc * 64 + l15;
  if (OUT_F32) {
    float* Cf = (float*)Cout;
#pragma unroll
    for (int mi = 0; mi < 4; ++mi)
#pragma unroll
      for (int ni = 0; ni < 4; ++ni)
#pragma unroll
        for (int r = 0; r < 4; ++r)
          Cf[(size_t)(row0 + mi * 16 + r) * N + col0 + ni * 16] = acc[mi][ni][r];
  } else {
    short* Cs = (short*)Cout;
#pragma unroll
    for (int mi = 0; mi < 4; ++mi)
#pragma unroll
      for (int ni = 0; ni < 4; ++ni)
#pragma unroll
        for (int r = 0; r < 4; ++r)
          Cs[(size_t)(row0 + mi * 16 + r) * N + col0 + ni * 16] = f2bf(acc[mi][ni][r]);
  }
}

// ---------------- flash attention: swapped-QK 32x32, in-register softmax --------
// grid (B*H=64, S/128=16); 4 waves x 32 q-rows. KVBLK=64 (2 kvt subtiles of 32).
// S^T = mfma(Kfrag, Qfrag): lane q=lane&31, hi=lane>>5; reg r -> kv=(r&3)+8*(r>>2)+4*hi.
// P redistribution to PV B-frag via cvt_pk + 4 shfl_xor(32) per kvt (layout derived
// from the m74/m101 C/D map; see round-4 notes).
__global__ __launch_bounds__(256) void attn_kernel(const short* __restrict__ Q,
                                                   const short* __restrict__ K,
                                                   const short* __restrict__ VT,
                                                   const short* __restrict__ biasT,
                                                   short* __restrict__ O) {
  __shared__ alignas(16) short Klds[64][64];
  __shared__ alignas(16) short Vtl[64][64];
  __shared__ alignas(16) short Bt[64][128];

  const int t = threadIdx.x;
  const int lane = t & 63, wave = t >> 6;
  const int b = blockIdx.x >> 4, h = blockIdx.x & 15;
  const int q0 = blockIdx.y * 128;
  const int l31 = lane & 31, hi = lane >> 5;

  const short* Qb = Q + (size_t)b * SS * DD + h * DHH;
  const short* Kb = K + (size_t)b * SS * DD + h * DHH;
  const short* VTb = VT + ((size_t)b * DD + h * DHH) * SS;
  const short* Bb = biasT + (size_t)b * SS * SS + q0;   // rows kv, col offset q0

  // Q fragments (B-operand): wave's q-row = q0 + wave*32 + l31, k=d = 16dc+8hi+j
  short8 qf[4];
  {
    int qrow = q0 + wave * 32 + l31;
#pragma unroll
    for (int dc = 0; dc < 4; ++dc)
      qf[dc] = *(const short8*)&Qb[(size_t)qrow * DD + dc * 16 + hi * 8];
  }

  floatx16 acc_pv[2];
#pragma unroll
  for (int dt = 0; dt < 2; ++dt)
#pragma unroll
    for (int r = 0; r < 16; ++r) acc_pv[dt][r] = 0.f;
  float mrun = -1e30f, ssum = 0.f;

  // staging: K/V 2 short8/thread, bias 4 short8/thread
  const int srow0 = t >> 3, sc = t & 7;
  const int srow1 = srow0 + 32;
  const int brow = t >> 4, bc = (t & 15) * 8;

  short8 kreg[2], vreg[2], breg[4];
  kreg[0] = *(const short8*)&Kb[(size_t)srow0 * DD + sc * 8];
  kreg[1] = *(const short8*)&Kb[(size_t)srow1 * DD + sc * 8];
  vreg[0] = *(const short8*)&VTb[(size_t)srow0 * SS + sc * 8];
  vreg[1] = *(const short8*)&VTb[(size_t)srow1 * SS + sc * 8];
#pragma unroll
  for (int i = 0; i < 4; ++i)
    breg[i] = *(const short8*)&Bb[(size_t)(brow + 16 * i) * SS + bc];

  for (int kv0 = 0; kv0 < SS; kv0 += 64) {
    __syncthreads();
    *(short8*)&Klds[srow0][(sc ^ (srow0 & 7)) * 8] = kreg[0];
    *(short8*)&Klds[srow1][(sc ^ (srow1 & 7)) * 8] = kreg[1];
    *(short8*)&Vtl[srow0][(sc ^ (srow0 & 7)) * 8] = vreg[0];
    *(short8*)&Vtl[srow1][(sc ^ (srow1 & 7)) * 8] = vreg[1];
#pragma unroll
    for (int i = 0; i < 4; ++i)
      *(short8*)&Bt[brow + 16 * i][bc] = breg[i];
    __syncthreads();

    if (kv0 + 64 < SS) {
      int kv1 = kv0 + 64;
      kreg[0] = *(const short8*)&Kb[(size_t)(kv1 + srow0) * DD + sc * 8];
      kreg[1] = *(const short8*)&Kb[(size_t)(kv1 + srow1) * DD + sc * 8];
      vreg[0] = *(const short8*)&VTb[(size_t)srow0 * SS + kv1 + sc * 8];
      vreg[1] = *(const short8*)&VTb[(size_t)srow1 * SS + kv1 + sc * 8];
#pragma unroll
      for (int i = 0; i < 4; ++i)
        breg[i] = *(const short8*)&Bb[(size_t)(kv1 + brow + 16 * i) * SS + bc];
    }

    // S^T = K·Q^T + bias (C-init from Bt)
    floatx16 sc_[2];
#pragma unroll
    for (int kvt = 0; kvt < 2; ++kvt) {
      floatx16 c;
#pragma unroll
      for (int r = 0; r < 16; ++r) {
        int krow = kvt * 32 + (r & 3) + 8 * (r >> 2) + 4 * hi;
        c[r] = bf2f(Bt[krow][wave * 32 + l31]);
      }
      int kr = kvt * 32 + l31;
#pragma unroll
      for (int dc = 0; dc < 4; ++dc) {
        short8 kf = *(const short8*)&Klds[kr][((2 * dc + hi) ^ (kr & 7)) * 8];
        c = __builtin_amdgcn_mfma_f32_32x32x16_bf16(kf, qf[dc], c, 0, 0, 0);
      }
      sc_[kvt] = c;
    }

    // row max (in-register + one cross-half exchange)
    float tmax = -1e30f;
#pragma unroll
    for (int kvt = 0; kvt < 2; ++kvt)
#pragma unroll
      for (int r = 0; r < 16; ++r) tmax = fmaxf(tmax, sc_[kvt][r]);
    tmax = fmaxf(tmax, __shfl_xor(tmax, 32));

    // defer-max rescale (THR=8 in log2 domain)
    if (tmax > mrun + 8.f) {
      float fac = __builtin_amdgcn_exp2f(mrun - tmax);
      ssum *= fac;
#pragma unroll
      for (int dt = 0; dt < 2; ++dt)
#pragma unroll
        for (int r = 0; r < 16; ++r) acc_pv[dt][r] *= fac;
      mrun = tmax;
    }

    float rsum = 0.f;
#pragma unroll
    for (int kvt = 0; kvt < 2; ++kvt)
#pragma unroll
      for (int r = 0; r < 16; ++r) {
        float p = __builtin_amdgcn_exp2f(sc_[kvt][r] - mrun);
        sc_[kvt][r] = p;
        rsum += p;
      }
    rsum += __shfl_xor(rsum, 32);
    ssum += rsum;

    // P -> bf16 + redistribute to PV B-frags; PV MFMAs
#pragma unroll
    for (int kvt = 0; kvt < 2; ++kvt) {
      int dd[8];
#pragma unroll
      for (int i = 0; i < 8; ++i) dd[i] = cvtpk(sc_[kvt][2 * i], sc_[kvt][2 * i + 1]);
      int rx[4];
      rx[0] = __shfl_xor(hi ? dd[0] : dd[2], 32);
      rx[1] = __shfl_xor(hi ? dd[1] : dd[3], 32);
      rx[2] = __shfl_xor(hi ? dd[4] : dd[6], 32);
      rx[3] = __shfl_xor(hi ? dd[5] : dd[7], 32);
#pragma unroll
      for (int ks2 = 0; ks2 < 2; ++ks2) {
        int4v w;
        w[0] = hi ? rx[2 * ks2]     : dd[4 * ks2];
        w[1] = hi ? rx[2 * ks2 + 1] : dd[4 * ks2 + 1];
        w[2] = hi ? dd[4 * ks2 + 2] : rx[2 * ks2];
        w[3] = hi ? dd[4 * ks2 + 3] : rx[2 * ks2 + 1];
        short8 pf = *(short8*)&w;
        int ks = kvt * 2 + ks2;
#pragma unroll
        for (int dt = 0; dt < 2; ++dt) {
          int vr = dt * 32 + l31;
          short8 vf = *(const short8*)&Vtl[vr][((2 * ks + hi) ^ (vr & 7)) * 8];
          acc_pv[dt] = __builtin_amdgcn_mfma_f32_32x32x16_bf16(vf, pf, acc_pv[dt], 0, 0, 0);
        }
      }
    }
  }

  // epilogue: O^T (regs) -> per-wave LDS transpose -> coalesced store
  __syncthreads();   // all waves done with Bt before reuse
  float inv = 1.0f / ssum;
  short* ep = &Bt[wave * 16][0];   // 4KB per wave, flat [32 q][64 d]
#pragma unroll
  for (int dt = 0; dt < 2; ++dt)
#pragma unroll
    for (int r = 0; r < 16; ++r) {
      int d = dt * 32 + (r & 3) + 8 * (r >> 2) + 4 * hi;
      int chunk = d >> 3, doff = d & 7;
      ep[l31 * 64 + ((chunk ^ (l31 & 7)) << 3) + doff] = f2bf(acc_pv[dt][r] * inv);
    }
  short* Ob = O + (size_t)b * SS * DD + h * DHH;
  const int rr = lane >> 3, cc = lane & 7;
#pragma unroll
  for (int ii = 0; ii < 4; ++ii) {
    int q = ii * 8 + rr;
    short8 vv = *(const short8*)&ep[q * 64 + ((cc ^ (q & 7)) << 3)];
    *(short8*)&Ob[(size_t)(q0 + wave * 32 + q) * DD + cc * 8] = vv;
  }
}

// ---------------- launch ----------------
extern "C" void kernel_launch(void* const* d_in, const int* in_sizes, int n_in,
                              void* d_out, int out_size, void* d_ws, size_t ws_size,
                              hipStream_t stream) {
  const float* qa   = (const float*)d_in[0];
  const float* ma   = (const float*)d_in[1];
  const float* bias = (const float*)d_in[2];
  const float* Wq   = (const float*)d_in[3];
  const float* Wk   = (const float*)d_in[4];
  const float* Wv   = (const float*)d_in[5];
  const float* Wo   = (const float*)d_in[6];
  float* out = (float*)d_out;

  char* ws = (char*)d_ws;
  size_t off = 0;
  auto alloc = [&](size_t bytes) {
    char* p = ws + off;
    off += (bytes + 255) & ~(size_t)255;
    return p;
  };
  const size_t nQKV = (size_t)BB * SS * DD;
  short* qa_bf   = (short*)alloc(nQKV * 2);
  short* ma_bf   = (short*)alloc(nQKV * 2);
  short* biasT   = (short*)alloc((size_t)BB * SS * SS * 2);
  short* Wqt = (short*)alloc((size_t)DD * DD * 2);
  short* Wkt = (short*)alloc((size_t)DD * DD * 2);
  short* Wvt = (short*)alloc((size_t)DD * DD * 2);
  short* Wot = (short*)alloc((size_t)DD * DD * 2);
  short* Qp  = (short*)alloc(nQKV * 2);
  short* Kp  = (short*)alloc(nQKV * 2);
  short* Vp  = (short*)alloc(nQKV * 2);
  short* AOp = (short*)alloc(nQKV * 2);
  short* VTp = qa_bf;  // reuse: qa_bf dead after Q-projection GEMM

  const float LOG2E = 1.4426950408889634f;
  int n4a = (int)(nQKV / 4);
  cvt_kernel<<<(n4a + 255) / 256, 256, 0, stream>>>(qa, qa_bf, n4a, 1.0f);
  cvt_kernel<<<(n4a + 255) / 256, 256, 0, stream>>>(ma, ma_bf, n4a, 1.0f);

  btrans_kernel<<<dim3(SS / 64, SS / 64, BB), 256, 0, stream>>>(bias, biasT, LOG2E);

  dim3 tg(64, 64);
  wtrans_kernel<<<tg, 256, 0, stream>>>(Wq, Wqt, 0.125f * LOG2E);
  wtrans_kernel<<<tg, 256, 0, stream>>>(Wk, Wkt, 1.0f);
  wtrans_kernel<<<tg, 256, 0, stream>>>(Wv, Wvt, 1.0f);
  wtrans_kernel<<<tg, 256, 0, stream>>>(Wo, Wot, 1.0f);

  dim3 gg(BB * SS / 128, DD / 128);
  gemm_kernel<0><<<gg, 256, 0, stream>>>(qa_bf, Wqt, Qp, BB * SS, DD, DD);
  gemm_kernel<0><<<gg, 256, 0, stream>>>(ma_bf, Wkt, Kp, BB * SS, DD, DD);
  gemm_kernel<0><<<gg, 256, 0, stream>>>(ma_bf, Wvt, Vp, BB * SS, DD, DD);

  vtrans_kernel<<<dim3(SS / 64, DD / 64, BB), 256, 0, stream>>>(Vp, VTp);

  attn_kernel<<<dim3(BB * HH, SS / 128), 256, 0, stream>>>(Qp, Kp, VTp, biasT, AOp);

  gemm_kernel<1><<<gg, 256, 0, stream>>>(AOp, Wot, out, BB * SS, DD, DD);
}

// Round 5
// 314.979 us; speedup vs baseline: 1.7070x; 1.1196x over previous
//
#include <hip/hip_runtime.h>
#include <hip/hip_bf16.h>

#define BB 4
#define SS 2048
#define DD 1024
#define HH 16
#define DHH 64

typedef __attribute__((ext_vector_type(8))) short short8;
typedef __attribute__((ext_vector_type(4))) float floatx4;
typedef __attribute__((ext_vector_type(16))) float floatx16;
typedef __attribute__((ext_vector_type(4))) int int4v;

__device__ inline short f2bf(float x) {
  union { float f; unsigned u; } v; v.f = x;
  unsigned r = v.u + 0x7FFFu + ((v.u >> 16) & 1u);
  return (short)(r >> 16);
}
__device__ inline float bf2f(short x) {
  union { unsigned u; float f; } v;
  v.u = ((unsigned)(unsigned short)x) << 16;
  return v.f;
}
__device__ inline int cvtpk(float lo, float hi) {
  int r;
  asm("v_cvt_pk_bf16_f32 %0, %1, %2" : "=v"(r) : "v"(lo), "v"(hi));
  return r;
}

typedef __attribute__((address_space(1))) const unsigned int GUI;
typedef __attribute__((address_space(3))) unsigned int LUI;
__device__ inline void gload16(const void* g, void* l) {
  __builtin_amdgcn_global_load_lds((GUI*)g, (LUI*)l, 16, 0, 0);
}

// ---------------- f32 -> bf16 conversion ----------------
__global__ __launch_bounds__(256) void cvt_kernel(const float* __restrict__ in,
                                                  short* __restrict__ out, int n4,
                                                  float scale) {
  int i = blockIdx.x * 256 + threadIdx.x;
  if (i >= n4) return;
  float4 v = ((const float4*)in)[i];
  short4 o;
  o.x = f2bf(v.x * scale); o.y = f2bf(v.y * scale);
  o.z = f2bf(v.z * scale); o.w = f2bf(v.w * scale);
  ((short4*)out)[i] = o;
}

// ---------------- weight transpose + convert (+scale) ----------------
__global__ __launch_bounds__(256) void wtrans_kernel(const float* __restrict__ in,
                                                     short* __restrict__ out, float scale) {
  __shared__ float tile[16][17];
  int tx = threadIdx.x & 15, ty = threadIdx.x >> 4;
  int k = blockIdx.y * 16 + ty;
  int n = blockIdx.x * 16 + tx;
  tile[ty][tx] = in[(size_t)k * 1024 + n];
  __syncthreads();
  int n2 = blockIdx.x * 16 + ty;
  int k2 = blockIdx.y * 16 + tx;
  out[(size_t)n2 * 1024 + k2] = f2bf(tile[tx][ty] * scale);
}

// ---------------- V transpose: [B][S][ldin] cols 0..1023 -> [B][1024][S] --------
__global__ __launch_bounds__(256) void vtrans_kernel(const short* __restrict__ in,
                                                     short* __restrict__ out, int ldin) {
  __shared__ int tile[64][33];
  const int t = threadIdx.x;
  const int b = blockIdx.z;
  const int s0 = blockIdx.x * 64, d0 = blockIdx.y * 64;
  const int* gin = (const int*)(in + (size_t)b * SS * ldin);
  const int ldi2 = ldin >> 1;
  int* gout = (int*)(out + (size_t)b * DD * SS);
#pragma unroll
  for (int i = 0; i < 8; ++i) {
    int idx = t + i * 256;
    int row = idx >> 5, col = idx & 31;
    tile[row][col] = gin[(size_t)(s0 + row) * ldi2 + (d0 >> 1) + col];
  }
  __syncthreads();
#pragma unroll
  for (int i = 0; i < 8; ++i) {
    int idx = t + i * 256;
    int d = idx >> 5, spc = idx & 31;
    int a = tile[2 * spc][d >> 1];
    int c = tile[2 * spc + 1][d >> 1];
    int o = (d & 1) ? (((a >> 16) & 0xffff) | (c & 0xffff0000))
                    : ((a & 0xffff) | (c << 16));
    gout[(size_t)(d0 + d) * (SS / 2) + (s0 >> 1) + spc] = o;
  }
}

// ---------------- bf16 MFMA GEMM, double-buffered 2-phase pipeline ----------------
// C[M,N] = A[M,K] @ Bt[N,K]^T. 128x128 tile, BK=32, stage(next) issued before
// compute(cur); single syncthreads (vmcnt drain) per K-step.
template<int OUT_F32>
__global__ __launch_bounds__(256) void gemm_kernel(const short* __restrict__ A,
                                                   const short* __restrict__ Bt,
                                                   void* __restrict__ Cout,
                                                   int M, int N, int K) {
  __shared__ alignas(16) short As[2][128][32];
  __shared__ alignas(16) short Bs[2][128][32];
  const int t = threadIdx.x;
  const int lane = t & 63, wave = t >> 6;
  const int wr = wave >> 1, wc = wave & 1;
  const int l15 = lane & 15, l4 = lane >> 4;

  floatx4 acc[4][4];
#pragma unroll
  for (int i = 0; i < 4; ++i)
#pragma unroll
    for (int j = 0; j < 4; ++j) acc[i][j] = (floatx4){0.f, 0.f, 0.f, 0.f};

  const short* Ag = A + (size_t)blockIdx.x * 128 * K;
  const short* Bg = Bt + (size_t)blockIdx.y * 128 * K;
  const int o0 = t * 16, o1 = t * 16 + 4096;
  const int r0 = o0 >> 6, c0 = (o0 >> 1) & 31;
  const int r1 = o1 >> 6, c1 = (o1 >> 1) & 31;
  const int rbase = wr * 64 + l15;
  const int cbase = wc * 64 + l15;
  const int koff = l4 * 8;

#define GSTAGE(buf, k0)                                                  \
  gload16(&Ag[(size_t)r0 * K + (k0) + c0], (char*)As[buf] + o0);         \
  gload16(&Bg[(size_t)r0 * K + (k0) + c0], (char*)Bs[buf] + o0);         \
  gload16(&Ag[(size_t)r1 * K + (k0) + c1], (char*)As[buf] + o1);         \
  gload16(&Bg[(size_t)r1 * K + (k0) + c1], (char*)Bs[buf] + o1);

  GSTAGE(0, 0)
  __syncthreads();
  int cur = 0;
  for (int k0 = 0; k0 < K; k0 += 32) {
    if (k0 + 32 < K) { GSTAGE(cur ^ 1, k0 + 32) }
    short8 af[4], bfr[4];
#pragma unroll
    for (int mi = 0; mi < 4; ++mi) af[mi] = *(const short8*)&As[cur][rbase + mi * 16][koff];
#pragma unroll
    for (int ni = 0; ni < 4; ++ni) bfr[ni] = *(const short8*)&Bs[cur][cbase + ni * 16][koff];
    __builtin_amdgcn_s_setprio(1);
#pragma unroll
    for (int mi = 0; mi < 4; ++mi)
#pragma unroll
      for (int ni = 0; ni < 4; ++ni)
        acc[mi][ni] = __builtin_amdgcn_mfma_f32_16x16x32_bf16(af[mi], bfr[ni], acc[mi][ni], 0, 0, 0);
    __builtin_amdgcn_s_setprio(0);
    __syncthreads();   // drains vmcnt for the prefetched tile + barrier
    cur ^= 1;
  }
#undef GSTAGE

  const int row0 = blockIdx.x * 128 + wr * 64 + l4 * 4;
  const int col0 = blockIdx.y * 128 + wc * 64 + l15;
  if (OUT_F32) {
    float* Cf = (float*)Cout;
#pragma unroll
    for (int mi = 0; mi < 4; ++mi)
#pragma unroll
      for (int ni = 0; ni < 4; ++ni)
#pragma unroll
        for (int r = 0; r < 4; ++r)
          Cf[(size_t)(row0 + mi * 16 + r) * N + col0 + ni * 16] = acc[mi][ni][r];
  } else {
    short* Cs = (short*)Cout;
#pragma unroll
    for (int mi = 0; mi < 4; ++mi)
#pragma unroll
      for (int ni = 0; ni < 4; ++ni)
#pragma unroll
        for (int r = 0; r < 4; ++r)
          Cs[(size_t)(row0 + mi * 16 + r) * N + col0 + ni * 16] = f2bf(acc[mi][ni][r]);
  }
}

// ---------------- flash attention: swapped-QK 32x32, in-register softmax --------
// grid (B*H=64, S/128=16); 4 waves x 32 q-rows. KVBLK=64.
// Bias stays [q][kv]: C-init kv index (r&3)+8*(r>>2)+4*hi is contiguous-4 in kv
// -> per lane 8x ds_read_b64, 4-lane broadcast, conflict-free. No global transpose.
__global__ __launch_bounds__(256) void attn_kernel(const short* __restrict__ Q,
                                                   const short* __restrict__ K,
                                                   const short* __restrict__ VT,
                                                   const short* __restrict__ biasb,
                                                   short* __restrict__ O, int ldk) {
  __shared__ alignas(16) short Klds[64][64];
  __shared__ alignas(16) short Vtl[64][64];
  __shared__ alignas(16) short Blds[128][64];

  const int t = threadIdx.x;
  const int lane = t & 63, wave = t >> 6;
  const int b = blockIdx.x >> 4, h = blockIdx.x & 15;
  const int q0 = blockIdx.y * 128;
  const int l31 = lane & 31, hi = lane >> 5;

  const short* Qb = Q + (size_t)b * SS * DD + h * DHH;
  const short* Kb = K + (size_t)b * SS * ldk + h * DHH;
  const short* VTb = VT + ((size_t)b * DD + h * DHH) * SS;
  const short* Bb = biasb + ((size_t)b * SS + q0) * SS;   // [128 q rows][S kv]

  short8 qf[4];
  {
    int qrow = q0 + wave * 32 + l31;
#pragma unroll
    for (int dc = 0; dc < 4; ++dc)
      qf[dc] = *(const short8*)&Qb[(size_t)qrow * DD + dc * 16 + hi * 8];
  }

  floatx16 acc_pv[2];
#pragma unroll
  for (int dt = 0; dt < 2; ++dt)
#pragma unroll
    for (int r = 0; r < 16; ++r) acc_pv[dt][r] = 0.f;
  float mrun = -1e30f, ssum = 0.f;

  const int srow0 = t >> 3, sc = t & 7;
  const int srow1 = srow0 + 32;

  short8 kreg[2], vreg[2], breg[4];
  kreg[0] = *(const short8*)&Kb[(size_t)srow0 * ldk + sc * 8];
  kreg[1] = *(const short8*)&Kb[(size_t)srow1 * ldk + sc * 8];
  vreg[0] = *(const short8*)&VTb[(size_t)srow0 * SS + sc * 8];
  vreg[1] = *(const short8*)&VTb[(size_t)srow1 * SS + sc * 8];
#pragma unroll
  for (int i = 0; i < 4; ++i) {
    int idx = t + 256 * i;
    breg[i] = *(const short8*)&Bb[(size_t)(idx >> 3) * SS + (idx & 7) * 8];
  }

  for (int kv0 = 0; kv0 < SS; kv0 += 64) {
    __syncthreads();
    *(short8*)&Klds[srow0][(sc ^ (srow0 & 7)) * 8] = kreg[0];
    *(short8*)&Klds[srow1][(sc ^ (srow1 & 7)) * 8] = kreg[1];
    *(short8*)&Vtl[srow0][(sc ^ (srow0 & 7)) * 8] = vreg[0];
    *(short8*)&Vtl[srow1][(sc ^ (srow1 & 7)) * 8] = vreg[1];
#pragma unroll
    for (int i = 0; i < 4; ++i) {
      int idx = t + 256 * i;
      int brow = idx >> 3, bch = idx & 7;
      *(short8*)&Blds[brow][(bch ^ (brow & 7)) * 8] = breg[i];
    }
    __syncthreads();

    if (kv0 + 64 < SS) {
      int kv1 = kv0 + 64;
      kreg[0] = *(const short8*)&Kb[(size_t)(kv1 + srow0) * ldk + sc * 8];
      kreg[1] = *(const short8*)&Kb[(size_t)(kv1 + srow1) * ldk + sc * 8];
      vreg[0] = *(const short8*)&VTb[(size_t)srow0 * SS + kv1 + sc * 8];
      vreg[1] = *(const short8*)&VTb[(size_t)srow1 * SS + kv1 + sc * 8];
#pragma unroll
      for (int i = 0; i < 4; ++i) {
        int idx = t + 256 * i;
        breg[i] = *(const short8*)&Bb[(size_t)(idx >> 3) * SS + kv1 + (idx & 7) * 8];
      }
    }

    // S^T = K·Q^T + bias (C-init via contiguous-4 b64 reads of untransposed bias)
    const int q = wave * 32 + l31;
    floatx16 sc_[2];
#pragma unroll
    for (int kvt = 0; kvt < 2; ++kvt) {
      floatx16 c;
#pragma unroll
      for (int g = 0; g < 4; ++g) {
        int ch = kvt * 4 + g;
        short4 b4 = *(const short4*)&Blds[q][((ch ^ (q & 7)) << 3) + hi * 4];
        c[4 * g + 0] = bf2f(b4.x);
        c[4 * g + 1] = bf2f(b4.y);
        c[4 * g + 2] = bf2f(b4.z);
        c[4 * g + 3] = bf2f(b4.w);
      }
      int kr = kvt * 32 + l31;
      __builtin_amdgcn_s_setprio(1);
#pragma unroll
      for (int dc = 0; dc < 4; ++dc) {
        short8 kf = *(const short8*)&Klds[kr][((2 * dc + hi) ^ (kr & 7)) * 8];
        c = __builtin_amdgcn_mfma_f32_32x32x16_bf16(kf, qf[dc], c, 0, 0, 0);
      }
      __builtin_amdgcn_s_setprio(0);
      sc_[kvt] = c;
    }

    float tmax = -1e30f;
#pragma unroll
    for (int kvt = 0; kvt < 2; ++kvt)
#pragma unroll
      for (int r = 0; r < 16; ++r) tmax = fmaxf(tmax, sc_[kvt][r]);
    tmax = fmaxf(tmax, __shfl_xor(tmax, 32));

    // defer-max rescale (THR=8, wave-uniform branch)
    if (__any(tmax > mrun + 8.f)) {
      float mnew = fmaxf(mrun, tmax);
      float fac = __builtin_amdgcn_exp2f(mrun - mnew);
      ssum *= fac;
#pragma unroll
      for (int dt = 0; dt < 2; ++dt)
#pragma unroll
        for (int r = 0; r < 16; ++r) acc_pv[dt][r] *= fac;
      mrun = mnew;
    }

    float rsum = 0.f;
#pragma unroll
    for (int kvt = 0; kvt < 2; ++kvt)
#pragma unroll
      for (int r = 0; r < 16; ++r) {
        float p = __builtin_amdgcn_exp2f(sc_[kvt][r] - mrun);
        sc_[kvt][r] = p;
        rsum += p;
      }
    rsum += __shfl_xor(rsum, 32);
    ssum += rsum;

    // P -> bf16, redistribute to PV B-frags, PV MFMAs
#pragma unroll
    for (int kvt = 0; kvt < 2; ++kvt) {
      int dd[8];
#pragma unroll
      for (int i = 0; i < 8; ++i) dd[i] = cvtpk(sc_[kvt][2 * i], sc_[kvt][2 * i + 1]);
      int rx[4];
      rx[0] = __shfl_xor(hi ? dd[0] : dd[2], 32);
      rx[1] = __shfl_xor(hi ? dd[1] : dd[3], 32);
      rx[2] = __shfl_xor(hi ? dd[4] : dd[6], 32);
      rx[3] = __shfl_xor(hi ? dd[5] : dd[7], 32);
#pragma unroll
      for (int ks2 = 0; ks2 < 2; ++ks2) {
        int4v w;
        w[0] = hi ? rx[2 * ks2]     : dd[4 * ks2];
        w[1] = hi ? rx[2 * ks2 + 1] : dd[4 * ks2 + 1];
        w[2] = hi ? dd[4 * ks2 + 2] : rx[2 * ks2];
        w[3] = hi ? dd[4 * ks2 + 3] : rx[2 * ks2 + 1];
        short8 pf = *(short8*)&w;
        int ks = kvt * 2 + ks2;
        __builtin_amdgcn_s_setprio(1);
#pragma unroll
        for (int dt = 0; dt < 2; ++dt) {
          int vr = dt * 32 + l31;
          short8 vf = *(const short8*)&Vtl[vr][((2 * ks + hi) ^ (vr & 7)) * 8];
          acc_pv[dt] = __builtin_amdgcn_mfma_f32_32x32x16_bf16(vf, pf, acc_pv[dt], 0, 0, 0);
        }
        __builtin_amdgcn_s_setprio(0);
      }
    }
  }

  // epilogue: O^T (regs) -> per-wave LDS transpose -> coalesced store
  __syncthreads();
  float inv = 1.0f / ssum;
  short* ep = &Blds[wave * 32][0];   // 4KB per wave, flat [32 q][64 d]
#pragma unroll
  for (int dt = 0; dt < 2; ++dt)
#pragma unroll
    for (int r = 0; r < 16; ++r) {
      int d = dt * 32 + (r & 3) + 8 * (r >> 2) + 4 * hi;
      int chunk = d >> 3, doff = d & 7;
      ep[l31 * 64 + ((chunk ^ (l31 & 7)) << 3) + doff] = f2bf(acc_pv[dt][r] * inv);
    }
  short* Ob = O + (size_t)b * SS * DD + h * DHH;
  const int rr = lane >> 3, cc = lane & 7;
#pragma unroll
  for (int ii = 0; ii < 4; ++ii) {
    int q2 = ii * 8 + rr;
    short8 vv = *(const short8*)&ep[q2 * 64 + ((cc ^ (q2 & 7)) << 3)];
    *(short8*)&Ob[(size_t)(q0 + wave * 32 + q2) * DD + cc * 8] = vv;
  }
}

// ---------------- launch ----------------
extern "C" void kernel_launch(void* const* d_in, const int* in_sizes, int n_in,
                              void* d_out, int out_size, void* d_ws, size_t ws_size,
                              hipStream_t stream) {
  const float* qa   = (const float*)d_in[0];
  const float* ma   = (const float*)d_in[1];
  const float* bias = (const float*)d_in[2];
  const float* Wq   = (const float*)d_in[3];
  const float* Wk   = (const float*)d_in[4];
  const float* Wv   = (const float*)d_in[5];
  const float* Wo   = (const float*)d_in[6];
  float* out = (float*)d_out;

  char* ws = (char*)d_ws;
  size_t off = 0;
  auto alloc = [&](size_t bytes) {
    char* p = ws + off;
    off += (bytes + 255) & ~(size_t)255;
    return p;
  };
  const size_t nQKV = (size_t)BB * SS * DD;
  short* qa_bf   = (short*)alloc(nQKV * 2);
  short* ma_bf   = (short*)alloc(nQKV * 2);
  short* bias_bf = (short*)alloc((size_t)BB * SS * SS * 2);
  short* Wqt  = (short*)alloc((size_t)DD * DD * 2);
  short* Wkvt = (short*)alloc((size_t)2 * DD * DD * 2);  // K rows then V rows
  short* Wot  = (short*)alloc((size_t)DD * DD * 2);
  short* Qp   = (short*)alloc(nQKV * 2);
  short* KVp  = (short*)alloc(nQKV * 2 * 2);             // [B*S][2048]: K | V
  short* AOp  = (short*)alloc(nQKV * 2);
  short* VTp  = qa_bf;  // reuse: qa_bf dead after Q-projection GEMM

  const float LOG2E = 1.4426950408889634f;
  int n4a = (int)(nQKV / 4);
  int n4b = BB * SS * SS / 4;
  cvt_kernel<<<(n4a + 255) / 256, 256, 0, stream>>>(qa, qa_bf, n4a, 1.0f);
  cvt_kernel<<<(n4a + 255) / 256, 256, 0, stream>>>(ma, ma_bf, n4a, 1.0f);
  cvt_kernel<<<(n4b + 255) / 256, 256, 0, stream>>>(bias, bias_bf, n4b, LOG2E);

  dim3 tg(64, 64);
  wtrans_kernel<<<tg, 256, 0, stream>>>(Wq, Wqt, 0.125f * LOG2E);
  wtrans_kernel<<<tg, 256, 0, stream>>>(Wk, Wkvt, 1.0f);
  wtrans_kernel<<<tg, 256, 0, stream>>>(Wv, Wkvt + (size_t)DD * DD, 1.0f);
  wtrans_kernel<<<tg, 256, 0, stream>>>(Wo, Wot, 1.0f);

  gemm_kernel<0><<<dim3(BB * SS / 128, DD / 128), 256, 0, stream>>>(qa_bf, Wqt, Qp, BB * SS, DD, DD);
  gemm_kernel<0><<<dim3(BB * SS / 128, 2 * DD / 128), 256, 0, stream>>>(ma_bf, Wkvt, KVp, BB * SS, 2 * DD, DD);

  vtrans_kernel<<<dim3(SS / 64, DD / 64, BB), 256, 0, stream>>>(KVp + DD, VTp, 2 * DD);

  attn_kernel<<<dim3(BB * HH, SS / 128), 256, 0, stream>>>(Qp, KVp, VTp, bias_bf, AOp, 2 * DD);

  gemm_kernel<1><<<dim3(BB * SS / 128, DD / 128), 256, 0, stream>>>(AOp, Wot, out, BB * SS, DD, DD);
}

// Round 6
// 309.922 us; speedup vs baseline: 1.7348x; 1.0163x over previous
//
#include <hip/hip_runtime.h>
#include <hip/hip_bf16.h>

#define BB 4
#define SS 2048
#define DD 1024
#define HH 16
#define DHH 64

typedef __attribute__((ext_vector_type(8))) short short8;
typedef __attribute__((ext_vector_type(4))) float floatx4;
typedef __attribute__((ext_vector_type(16))) float floatx16;
typedef __attribute__((ext_vector_type(4))) int int4v;

__device__ inline short f2bf(float x) {
  union { float f; unsigned u; } v; v.f = x;
  unsigned r = v.u + 0x7FFFu + ((v.u >> 16) & 1u);
  return (short)(r >> 16);
}
__device__ inline float bf2f(short x) {
  union { unsigned u; float f; } v;
  v.u = ((unsigned)(unsigned short)x) << 16;
  return v.f;
}
__device__ inline int cvtpk(float lo, float hi) {
  int r;
  asm("v_cvt_pk_bf16_f32 %0, %1, %2" : "=v"(r) : "v"(lo), "v"(hi));
  return r;
}
// DST[63:32] <-> SRC[31:0]: a' = {a.lo, b.lo}, b' = {a.hi, b.hi}
__device__ inline void pl32swap(int& a, int& b) {
  asm("v_permlane32_swap_b32 %0, %1" : "+v"(a), "+v"(b));
}

typedef __attribute__((address_space(1))) const unsigned int GUI;
typedef __attribute__((address_space(3))) unsigned int LUI;
__device__ inline void gload16(const void* g, void* l) {
  __builtin_amdgcn_global_load_lds((GUI*)g, (LUI*)l, 16, 0, 0);
}

// ---------------- f32 -> bf16 conversion ----------------
__global__ __launch_bounds__(256) void cvt_kernel(const float* __restrict__ in,
                                                  short* __restrict__ out, int n4,
                                                  float scale) {
  int i = blockIdx.x * 256 + threadIdx.x;
  if (i >= n4) return;
  float4 v = ((const float4*)in)[i];
  short4 o;
  o.x = f2bf(v.x * scale); o.y = f2bf(v.y * scale);
  o.z = f2bf(v.z * scale); o.w = f2bf(v.w * scale);
  ((short4*)out)[i] = o;
}

// ---------------- weight transpose + convert (+scale) ----------------
__global__ __launch_bounds__(256) void wtrans_kernel(const float* __restrict__ in,
                                                     short* __restrict__ out, float scale) {
  __shared__ float tile[16][17];
  int tx = threadIdx.x & 15, ty = threadIdx.x >> 4;
  int k = blockIdx.y * 16 + ty;
  int n = blockIdx.x * 16 + tx;
  tile[ty][tx] = in[(size_t)k * 1024 + n];
  __syncthreads();
  int n2 = blockIdx.x * 16 + ty;
  int k2 = blockIdx.y * 16 + tx;
  out[(size_t)n2 * 1024 + k2] = f2bf(tile[tx][ty] * scale);
}

// ---------------- V transpose: [B][S][ldin] cols 0..1023 -> [B][1024][S] --------
__global__ __launch_bounds__(256) void vtrans_kernel(const short* __restrict__ in,
                                                     short* __restrict__ out, int ldin) {
  __shared__ int tile[64][33];
  const int t = threadIdx.x;
  const int b = blockIdx.z;
  const int s0 = blockIdx.x * 64, d0 = blockIdx.y * 64;
  const int* gin = (const int*)(in + (size_t)b * SS * ldin);
  const int ldi2 = ldin >> 1;
  int* gout = (int*)(out + (size_t)b * DD * SS);
#pragma unroll
  for (int i = 0; i < 8; ++i) {
    int idx = t + i * 256;
    int row = idx >> 5, col = idx & 31;
    tile[row][col] = gin[(size_t)(s0 + row) * ldi2 + (d0 >> 1) + col];
  }
  __syncthreads();
#pragma unroll
  for (int i = 0; i < 8; ++i) {
    int idx = t + i * 256;
    int d = idx >> 5, spc = idx & 31;
    int a = tile[2 * spc][d >> 1];
    int c = tile[2 * spc + 1][d >> 1];
    int o = (d & 1) ? (((a >> 16) & 0xffff) | (c & 0xffff0000))
                    : ((a & 0xffff) | (c << 16));
    gout[(size_t)(d0 + d) * (SS / 2) + (s0 >> 1) + spc] = o;
  }
}

// ---------------- bf16 MFMA GEMM, double-buffered 2-phase, XCD-swizzled ---------
// 1-D grid nwg = (M/128)*(N/128), nwg % 8 == 0.
template<int OUT_F32>
__global__ __launch_bounds__(256) void gemm_kernel(const short* __restrict__ A,
                                                   const short* __restrict__ Bt,
                                                   void* __restrict__ Cout,
                                                   int M, int N, int K) {
  __shared__ alignas(16) short As[2][128][32];
  __shared__ alignas(16) short Bs[2][128][32];
  const int t = threadIdx.x;
  const int lane = t & 63, wave = t >> 6;
  const int wr = wave >> 1, wc = wave & 1;
  const int l15 = lane & 15, l4 = lane >> 4;

  // XCD-chunked swizzle; logical order: N-tile fastest (A-panel sharers adjacent)
  const int hw = blockIdx.x;
  const int L = (hw & 7) * ((int)gridDim.x >> 3) + (hw >> 3);
  const int NY = N >> 7;
  const int bxm = L / NY, byn = L % NY;

  floatx4 acc[4][4];
#pragma unroll
  for (int i = 0; i < 4; ++i)
#pragma unroll
    for (int j = 0; j < 4; ++j) acc[i][j] = (floatx4){0.f, 0.f, 0.f, 0.f};

  const short* Ag = A + (size_t)bxm * 128 * K;
  const short* Bg = Bt + (size_t)byn * 128 * K;
  const int o0 = t * 16, o1 = t * 16 + 4096;
  const int r0 = o0 >> 6, c0 = (o0 >> 1) & 31;
  const int r1 = o1 >> 6, c1 = (o1 >> 1) & 31;
  const int rbase = wr * 64 + l15;
  const int cbase = wc * 64 + l15;
  const int koff = l4 * 8;

#define GSTAGE(buf, k0)                                                  \
  gload16(&Ag[(size_t)r0 * K + (k0) + c0], (char*)As[buf] + o0);         \
  gload16(&Bg[(size_t)r0 * K + (k0) + c0], (char*)Bs[buf] + o0);         \
  gload16(&Ag[(size_t)r1 * K + (k0) + c1], (char*)As[buf] + o1);         \
  gload16(&Bg[(size_t)r1 * K + (k0) + c1], (char*)Bs[buf] + o1);

  GSTAGE(0, 0)
  __syncthreads();
  int cur = 0;
  for (int k0 = 0; k0 < K; k0 += 32) {
    if (k0 + 32 < K) { GSTAGE(cur ^ 1, k0 + 32) }
    short8 af[4], bfr[4];
#pragma unroll
    for (int mi = 0; mi < 4; ++mi) af[mi] = *(const short8*)&As[cur][rbase + mi * 16][koff];
#pragma unroll
    for (int ni = 0; ni < 4; ++ni) bfr[ni] = *(const short8*)&Bs[cur][cbase + ni * 16][koff];
    __builtin_amdgcn_s_setprio(1);
#pragma unroll
    for (int mi = 0; mi < 4; ++mi)
#pragma unroll
      for (int ni = 0; ni < 4; ++ni)
        acc[mi][ni] = __builtin_amdgcn_mfma_f32_16x16x32_bf16(af[mi], bfr[ni], acc[mi][ni], 0, 0, 0);
    __builtin_amdgcn_s_setprio(0);
    __syncthreads();
    cur ^= 1;
  }
#undef GSTAGE

  const int row0 = bxm * 128 + wr * 64 + l4 * 4;
  const int col0 = byn * 128 + wc * 64 + l15;
  if (OUT_F32) {
    float* Cf = (float*)Cout;
#pragma unroll
    for (int mi = 0; mi < 4; ++mi)
#pragma unroll
      for (int ni = 0; ni < 4; ++ni)
#pragma unroll
        for (int r = 0; r < 4; ++r)
          Cf[(size_t)(row0 + mi * 16 + r) * N + col0 + ni * 16] = acc[mi][ni][r];
  } else {
    short* Cs = (short*)Cout;
#pragma unroll
    for (int mi = 0; mi < 4; ++mi)
#pragma unroll
      for (int ni = 0; ni < 4; ++ni)
#pragma unroll
        for (int r = 0; r < 4; ++r)
          Cs[(size_t)(row0 + mi * 16 + r) * N + col0 + ni * 16] = f2bf(acc[mi][ni][r]);
  }
}

// ---------------- flash attention: DMA-staged, MFMA-sum, permlane P-swap --------
// 1-D grid 1024, XCD-chunked. 4 waves x 32 q. KVBLK=64, LDS double-buffered.
__global__ __launch_bounds__(256) void attn_kernel(const short* __restrict__ Q,
                                                   const short* __restrict__ K,
                                                   const short* __restrict__ VT,
                                                   const short* __restrict__ biasb,
                                                   short* __restrict__ O, int ldk) {
  __shared__ alignas(16) short Klds[2][64][64];    // 16KB
  __shared__ alignas(16) short Vtl[2][64][64];     // 16KB
  __shared__ alignas(16) short Blds[2][128][64];   // 32KB

  const int t = threadIdx.x;
  const int lane = t & 63, wave = t >> 6;
  // XCD swizzle: logical L; q0-tiles of one (b,h) contiguous -> same XCD
  const int hw = blockIdx.x;
  const int L = (hw & 7) * 128 + (hw >> 3);
  const int bh = L >> 4;
  const int q0 = (L & 15) * 128;
  const int b = bh >> 4, h = bh & 15;
  const int l31 = lane & 31, hi = lane >> 5;

  const short* Qb = Q + (size_t)b * SS * DD + h * DHH;
  const short* Kb = K + (size_t)b * SS * ldk + h * DHH;
  const short* VTb = VT + ((size_t)b * DD + h * DHH) * SS;
  const short* Bb = biasb + ((size_t)b * SS + q0) * SS;

  // staging geometry: lane t -> LDS row t>>3 (+32/+64/+96), chunk t&7;
  // global source chunk pre-swizzled: (t&7) ^ (row&7); rows differ by 32 -> same &7
  const int sr0 = t >> 3;
  const int scb = ((t & 7) ^ (sr0 & 7)) * 8;

#define ATTN_STAGE(buf, kvb)                                                            \
  {                                                                                     \
    gload16(&Kb[(size_t)((kvb) + sr0) * ldk + scb], (char*)&Klds[buf][0][0] + t * 16);  \
    gload16(&Kb[(size_t)((kvb) + sr0 + 32) * ldk + scb],                                \
            (char*)&Klds[buf][0][0] + 4096 + t * 16);                                   \
    gload16(&VTb[(size_t)sr0 * SS + (kvb) + scb], (char*)&Vtl[buf][0][0] + t * 16);     \
    gload16(&VTb[(size_t)(sr0 + 32) * SS + (kvb) + scb],                                \
            (char*)&Vtl[buf][0][0] + 4096 + t * 16);                                    \
    gload16(&Bb[(size_t)sr0 * SS + (kvb) + scb], (char*)&Blds[buf][0][0] + t * 16);     \
    gload16(&Bb[(size_t)(sr0 + 32) * SS + (kvb) + scb],                                 \
            (char*)&Blds[buf][0][0] + 4096 + t * 16);                                   \
    gload16(&Bb[(size_t)(sr0 + 64) * SS + (kvb) + scb],                                 \
            (char*)&Blds[buf][0][0] + 8192 + t * 16);                                   \
    gload16(&Bb[(size_t)(sr0 + 96) * SS + (kvb) + scb],                                 \
            (char*)&Blds[buf][0][0] + 12288 + t * 16);                                  \
  }

  ATTN_STAGE(0, 0)

  short8 qf[4];
  {
    int qrow = q0 + wave * 32 + l31;
#pragma unroll
    for (int dc = 0; dc < 4; ++dc)
      qf[dc] = *(const short8*)&Qb[(size_t)qrow * DD + dc * 16 + hi * 8];
  }
  short8 onesf;
#pragma unroll
  for (int i = 0; i < 8; ++i) onesf[i] = (short)0x3F80;  // bf16 1.0

  floatx16 acc_pv[2], acc_sum;
#pragma unroll
  for (int r = 0; r < 16; ++r) { acc_pv[0][r] = 0.f; acc_pv[1][r] = 0.f; acc_sum[r] = 0.f; }
  float mrun = -1e30f;

  const int q = wave * 32 + l31;
  const int qsw = q & 7;

  __syncthreads();
  int cur = 0;
  for (int kv0 = 0; kv0 < SS; kv0 += 64) {
    if (kv0 + 64 < SS) ATTN_STAGE(cur ^ 1, kv0 + 64)

    // S^T = K·Q^T + bias (C-init: b64 reads of bias tile, kv contiguous-4)
    floatx16 sc_[2];
#pragma unroll
    for (int kvt = 0; kvt < 2; ++kvt) {
      floatx16 c;
#pragma unroll
      for (int g = 0; g < 4; ++g) {
        int ch = kvt * 4 + g;
        short4 b4 = *(const short4*)&Blds[cur][q][((ch ^ qsw) << 3) + hi * 4];
        c[4 * g + 0] = bf2f(b4.x);
        c[4 * g + 1] = bf2f(b4.y);
        c[4 * g + 2] = bf2f(b4.z);
        c[4 * g + 3] = bf2f(b4.w);
      }
      int kr = kvt * 32 + l31;
      __builtin_amdgcn_s_setprio(1);
#pragma unroll
      for (int dc = 0; dc < 4; ++dc) {
        short8 kf = *(const short8*)&Klds[cur][kr][((2 * dc + hi) ^ (kr & 7)) * 8];
        c = __builtin_amdgcn_mfma_f32_32x32x16_bf16(kf, qf[dc], c, 0, 0, 0);
      }
      __builtin_amdgcn_s_setprio(0);
      sc_[kvt] = c;
    }

    // row max: parallel tree (depth 5) + one cross-half exchange
    float m8[8];
#pragma unroll
    for (int i = 0; i < 8; ++i)
      m8[i] = fmaxf(fmaxf(sc_[0][i], sc_[0][i + 8]), fmaxf(sc_[1][i], sc_[1][i + 8]));
#pragma unroll
    for (int i = 0; i < 4; ++i) m8[i] = fmaxf(m8[i], m8[i + 4]);
    float tmax = fmaxf(fmaxf(m8[0], m8[1]), fmaxf(m8[2], m8[3]));
    tmax = fmaxf(tmax, __shfl_xor(tmax, 32));

    // defer-max rescale (THR=8 in log2 domain, wave-uniform)
    if (__any(tmax > mrun + 8.f)) {
      float mnew = fmaxf(mrun, tmax);
      float fac = __builtin_amdgcn_exp2f(mrun - mnew);
      acc_sum[0] *= fac;
#pragma unroll
      for (int dt = 0; dt < 2; ++dt)
#pragma unroll
        for (int r = 0; r < 16; ++r) acc_pv[dt][r] *= fac;
      mrun = mnew;
    }

#pragma unroll
    for (int kvt = 0; kvt < 2; ++kvt)
#pragma unroll
      for (int r = 0; r < 16; ++r)
        sc_[kvt][r] = __builtin_amdgcn_exp2f(sc_[kvt][r] - mrun);

    // P -> bf16; permlane32_swap assembles PV B-frags; PV + sum MFMAs
#pragma unroll
    for (int kvt = 0; kvt < 2; ++kvt) {
      int dd[8];
#pragma unroll
      for (int i = 0; i < 8; ++i) dd[i] = cvtpk(sc_[kvt][2 * i], sc_[kvt][2 * i + 1]);
#pragma unroll
      for (int ks2 = 0; ks2 < 2; ++ks2) {
        int a0 = dd[4 * ks2 + 0], a1 = dd[4 * ks2 + 1];
        int a2 = dd[4 * ks2 + 2], a3 = dd[4 * ks2 + 3];
        pl32swap(a0, a2);   // a0 = w0, a2 = w2
        pl32swap(a1, a3);   // a1 = w1, a3 = w3
        int4v w; w[0] = a0; w[1] = a1; w[2] = a2; w[3] = a3;
        short8 pf = *(short8*)&w;
        int ks = kvt * 2 + ks2;
        __builtin_amdgcn_s_setprio(1);
#pragma unroll
        for (int dt = 0; dt < 2; ++dt) {
          int vr = dt * 32 + l31;
          short8 vf = *(const short8*)&Vtl[cur][vr][((2 * ks + hi) ^ (vr & 7)) * 8];
          acc_pv[dt] = __builtin_amdgcn_mfma_f32_32x32x16_bf16(vf, pf, acc_pv[dt], 0, 0, 0);
        }
        acc_sum = __builtin_amdgcn_mfma_f32_32x32x16_bf16(onesf, pf, acc_sum, 0, 0, 0);
        __builtin_amdgcn_s_setprio(0);
      }
    }
    __syncthreads();
    cur ^= 1;
  }
#undef ATTN_STAGE

  // epilogue: O^T (regs) -> per-wave LDS transpose -> coalesced store
  float inv = 1.0f / acc_sum[0];
  short* ep = (short*)Klds + wave * 2048;   // 4KB per wave, flat [32 q][64 d]
#pragma unroll
  for (int dt = 0; dt < 2; ++dt)
#pragma unroll
    for (int r = 0; r < 16; ++r) {
      int d = dt * 32 + (r & 3) + 8 * (r >> 2) + 4 * hi;
      int chunk = d >> 3, doff = d & 7;
      ep[l31 * 64 + ((chunk ^ (l31 & 7)) << 3) + doff] = f2bf(acc_pv[dt][r] * inv);
    }
  short* Ob = O + (size_t)b * SS * DD + h * DHH;
  const int rr = lane >> 3, cc = lane & 7;
#pragma unroll
  for (int ii = 0; ii < 4; ++ii) {
    int q2 = ii * 8 + rr;
    short8 vv = *(const short8*)&ep[q2 * 64 + ((cc ^ (q2 & 7)) << 3)];
    *(short8*)&Ob[(size_t)(q0 + wave * 32 + q2) * DD + cc * 8] = vv;
  }
}

// ---------------- launch ----------------
extern "C" void kernel_launch(void* const* d_in, const int* in_sizes, int n_in,
                              void* d_out, int out_size, void* d_ws, size_t ws_size,
                              hipStream_t stream) {
  const float* qa   = (const float*)d_in[0];
  const float* ma   = (const float*)d_in[1];
  const float* bias = (const float*)d_in[2];
  const float* Wq   = (const float*)d_in[3];
  const float* Wk   = (const float*)d_in[4];
  const float* Wv   = (const float*)d_in[5];
  const float* Wo   = (const float*)d_in[6];
  float* out = (float*)d_out;

  char* ws = (char*)d_ws;
  size_t off = 0;
  auto alloc = [&](size_t bytes) {
    char* p = ws + off;
    off += (bytes + 255) & ~(size_t)255;
    return p;
  };
  const size_t nQKV = (size_t)BB * SS * DD;
  short* qa_bf   = (short*)alloc(nQKV * 2);
  short* ma_bf   = (short*)alloc(nQKV * 2);
  short* bias_bf = (short*)alloc((size_t)BB * SS * SS * 2);
  short* Wqt  = (short*)alloc((size_t)DD * DD * 2);
  short* Wkvt = (short*)alloc((size_t)2 * DD * DD * 2);  // K rows then V rows
  short* Wot  = (short*)alloc((size_t)DD * DD * 2);
  short* Qp   = (short*)alloc(nQKV * 2);
  short* KVp  = (short*)alloc(nQKV * 2 * 2);             // [B*S][2048]: K | V
  short* AOp  = (short*)alloc(nQKV * 2);
  short* VTp  = qa_bf;  // reuse: qa_bf dead after Q-projection GEMM

  const float LOG2E = 1.4426950408889634f;
  int n4a = (int)(nQKV / 4);
  int n4b = BB * SS * SS / 4;
  cvt_kernel<<<(n4a + 255) / 256, 256, 0, stream>>>(qa, qa_bf, n4a, 1.0f);
  cvt_kernel<<<(n4a + 255) / 256, 256, 0, stream>>>(ma, ma_bf, n4a, 1.0f);
  cvt_kernel<<<(n4b + 255) / 256, 256, 0, stream>>>(bias, bias_bf, n4b, LOG2E);

  dim3 tg(64, 64);
  wtrans_kernel<<<tg, 256, 0, stream>>>(Wq, Wqt, 0.125f * LOG2E);
  wtrans_kernel<<<tg, 256, 0, stream>>>(Wk, Wkvt, 1.0f);
  wtrans_kernel<<<tg, 256, 0, stream>>>(Wv, Wkvt + (size_t)DD * DD, 1.0f);
  wtrans_kernel<<<tg, 256, 0, stream>>>(Wo, Wot, 1.0f);

  gemm_kernel<0><<<BB * SS / 128 * (DD / 128), 256, 0, stream>>>(qa_bf, Wqt, Qp, BB * SS, DD, DD);
  gemm_kernel<0><<<BB * SS / 128 * (2 * DD / 128), 256, 0, stream>>>(ma_bf, Wkvt, KVp, BB * SS, 2 * DD, DD);

  vtrans_kernel<<<dim3(SS / 64, DD / 64, BB), 256, 0, stream>>>(KVp + DD, VTp, 2 * DD);

  attn_kernel<<<BB * HH * (SS / 128), 256, 0, stream>>>(Qp, KVp, VTp, bias_bf, AOp, 2 * DD);

  gemm_kernel<1><<<BB * SS / 128 * (DD / 128), 256, 0, stream>>>(AOp, Wot, out, BB * SS, DD, DD);
}